// Round 3
// baseline (1436.033 us; speedup 1.0000x reference)
//
#include <hip/hip_runtime.h>
#include <stdint.h>

// GCN layer: out = relu( segment_sum(vals * emb[cols], rows) @ W )
// Correctness-first rebuild:
//  - NO mfma builtins / __bf16 / SFINAE (suspected compile-failure source in
//    rounds 0-1: output was bit-identical to the no-op stub both times).
//  - Runtime dtype detection (f32 vs bf16) from adj_vals' bit pattern; every
//    dtype-dependent kernel is launched in both flavors, gated on the flag.
//  - CSR build (hist/scan/scatter) -> per-node gather aggregation (no float
//    atomics) -> VALU f32 GEMM + ReLU. MFMA comes back once this passes.

typedef unsigned short u16;

__device__ __forceinline__ float b2f(u16 u) {
  union { unsigned i; float f; } x; x.i = ((unsigned)u) << 16; return x.f;
}
__device__ __forceinline__ u16 f2b(float f) {
  union { unsigned i; float f; } x; x.f = f;
  unsigned r = x.i + 0x7fffu + ((x.i >> 16) & 1u);
  return (u16)(r >> 16);
}

// ---- dtype detect: adj_vals ~ U[0,1).  As f32 words, low16 bits are uniform
// (>=0x3F80 ~75% of the time). As packed bf16 pairs, low16 is itself a bf16 in
// [0,1) -> < 0x3F80 (except exact 1.0 roundings, ~0.2%). flag: 1=bf16, 0=f32.
__global__ void detect_k(const unsigned* __restrict__ valsw, int* __restrict__ flag) {
  __shared__ int cnt;
  if (threadIdx.x == 0) cnt = 0;
  __syncthreads();
  int c = 0;
  for (int i = threadIdx.x; i < 4096; i += 256) {
    unsigned w = valsw[i];
    if ((w & 0xFFFFu) >= 0x3F80u) c++;
  }
  atomicAdd(&cnt, c);
  __syncthreads();
  if (threadIdx.x == 0) *flag = (cnt < 1024) ? 1 : 0;
}

// ---------------- CSR build (dtype-independent parts) ----------------

__global__ void hist_k(const int* __restrict__ rows, int* __restrict__ counts, int E) {
  int i = blockIdx.x * blockDim.x + threadIdx.x;
  if (i < E) atomicAdd(&counts[rows[i]], 1);
}

__global__ __launch_bounds__(1024) void scan_k(const int* __restrict__ counts,
                                               int* __restrict__ offs,
                                               int* __restrict__ cursor, int N) {
  __shared__ int part[1024];
  int tid = threadIdx.x;
  int chunk = (N + 1023) >> 10;
  int lo = tid * chunk;
  int hi = lo + chunk;
  if (hi > N) hi = N;
  if (lo > N) lo = N;
  int s = 0;
  for (int i = lo; i < hi; ++i) s += counts[i];
  part[tid] = s;
  __syncthreads();
  if (tid == 0) {
    int run = 0;
    for (int i = 0; i < 1024; ++i) { int t = part[i]; part[i] = run; run += t; }
  }
  __syncthreads();
  int run = part[tid];
  for (int i = lo; i < hi; ++i) { offs[i] = run; cursor[i] = run; run += counts[i]; }
  if (tid == 1023) offs[N] = run;  // chunks past N are empty -> run == E
}

template <bool BF16>
__global__ void scatter_k(const int* __restrict__ flag, const int* __restrict__ rows,
                          const int* __restrict__ cols, const void* __restrict__ valsv,
                          int* __restrict__ cursor, int* __restrict__ ccol,
                          float* __restrict__ cval, int E) {
  if (*flag != (BF16 ? 1 : 0)) return;
  int i = blockIdx.x * blockDim.x + threadIdx.x;
  if (i < E) {
    int r = rows[i];
    int p = atomicAdd(&cursor[r], 1);
    ccol[p] = cols[i];
    cval[p] = BF16 ? b2f(((const u16*)valsv)[i]) : ((const float*)valsv)[i];
  }
}

// ---------------- W -> f32 copy ----------------
template <bool BF16>
__global__ void wconv_k(const int* __restrict__ flag, const void* __restrict__ Wv,
                        float* __restrict__ Wc) {
  if (*flag != (BF16 ? 1 : 0)) return;
  int i = blockIdx.x * blockDim.x + threadIdx.x;  // 65536 total
  Wc[i] = BF16 ? b2f(((const u16*)Wv)[i]) : ((const float*)Wv)[i];
}

// ---------------- aggregation: one wave per node, no atomics ----------------
// agg (bf16) rows: agg[n][d] = sum_{e in CSR row n} val_e * emb[col_e][d]
template <bool BF16>
__global__ void agg_k(const int* __restrict__ flag, const void* __restrict__ embv,
                      const int* __restrict__ offs, const int* __restrict__ ccol,
                      const float* __restrict__ cval, u16* __restrict__ agg, int N) {
  if (*flag != (BF16 ? 1 : 0)) return;
  int wave = threadIdx.x >> 6, lane = threadIdx.x & 63;
  int node = blockIdx.x * 4 + wave;
  if (node >= N) return;
  int beg = offs[node], end = offs[node + 1];
  float a0 = 0.f, a1 = 0.f, a2 = 0.f, a3 = 0.f;
  if (BF16) {
    const u16* eb = (const u16*)embv + lane * 4;
    for (int j = beg; j < end; ++j) {
      int c = ccol[j];
      float v = cval[j];
      ushort4 e = *(const ushort4*)(eb + (size_t)c * 256);
      a0 += v * b2f(e.x); a1 += v * b2f(e.y);
      a2 += v * b2f(e.z); a3 += v * b2f(e.w);
    }
  } else {
    const float* eb = (const float*)embv + lane * 4;
    for (int j = beg; j < end; ++j) {
      int c = ccol[j];
      float v = cval[j];
      float4 e = *(const float4*)(eb + (size_t)c * 256);
      a0 += v * e.x; a1 += v * e.y; a2 += v * e.z; a3 += v * e.w;
    }
  }
  ushort4 o;
  o.x = f2b(a0); o.y = f2b(a1); o.z = f2b(a2); o.w = f2b(a3);
  *(ushort4*)(agg + (size_t)node * 256 + lane * 4) = o;
}

// ---------------- VALU GEMM + ReLU: out = relu(agg @ Wc) ----------------
// 256 threads/block, 16 nodes/block. Thread t owns output column t for all 16
// nodes. Wc reads are coalesced; As reads are wave-uniform broadcasts.
template <bool OUTBF16>
__global__ __launch_bounds__(256) void gemm_k(const int* __restrict__ flag,
                                              const u16* __restrict__ agg,
                                              const float* __restrict__ Wc,
                                              void* __restrict__ outv, int N) {
  if (*flag != (OUTBF16 ? 1 : 0)) return;
  __shared__ float As[16 * 256];  // 16 KB
  int tid = threadIdx.x;
  int m0 = blockIdx.x * 16;
#pragma unroll
  for (int i = 0; i < 16; ++i) {
    float v = 0.f;
    if (m0 + i < N) v = b2f(agg[(size_t)(m0 + i) * 256 + tid]);
    As[i * 256 + tid] = v;
  }
  __syncthreads();

  float acc[16];
#pragma unroll
  for (int r = 0; r < 16; ++r) acc[r] = 0.f;

  for (int kk = 0; kk < 256; kk += 4) {
    float w0 = Wc[(kk + 0) * 256 + tid];
    float w1 = Wc[(kk + 1) * 256 + tid];
    float w2 = Wc[(kk + 2) * 256 + tid];
    float w3 = Wc[(kk + 3) * 256 + tid];
#pragma unroll
    for (int r = 0; r < 16; ++r) {
      float4 a = *(const float4*)&As[r * 256 + kk];  // broadcast, 16B aligned
      acc[r] += a.x * w0 + a.y * w1 + a.z * w2 + a.w * w3;
    }
  }

#pragma unroll
  for (int r = 0; r < 16; ++r) {
    int m = m0 + r;
    if (m < N) {
      float v = acc[r];
      v = v > 0.f ? v : 0.f;
      if (OUTBF16) ((u16*)outv)[(size_t)m * 256 + tid] = f2b(v);
      else         ((float*)outv)[(size_t)m * 256 + tid] = v;
    }
  }
}

// ---------------- launch ----------------

extern "C" void kernel_launch(void* const* d_in, const int* in_sizes, int n_in,
                              void* d_out, int out_size, void* d_ws, size_t ws_size,
                              hipStream_t stream) {
  const void* emb  = d_in[0];
  const int*  rows = (const int*)d_in[1];
  const int*  cols = (const int*)d_in[2];
  const void* vals = d_in[3];
  const void* W    = d_in[4];

  int N = in_sizes[0] / 256;
  int E = in_sizes[1];

  char* ws = (char*)d_ws;
  size_t off = 0;
  auto carve = [&](size_t bytes) -> char* {
    char* p = ws + off;
    off += (bytes + 511) & ~(size_t)511;
    return p;
  };
  int*   flag   = (int*)  carve(4);
  int*   counts = (int*)  carve((size_t)N * 4);
  int*   offs   = (int*)  carve((size_t)(N + 1) * 4);
  int*   cursor = (int*)  carve((size_t)N * 4);
  int*   ccol   = (int*)  carve((size_t)E * 4);
  float* cval   = (float*)carve((size_t)E * 4);
  u16*   agg    = (u16*)  carve((size_t)N * 256 * 2);
  float* Wc     = (float*)carve((size_t)256 * 256 * 4);
  (void)ws_size; (void)n_in; (void)out_size;  // ~79 MB carved

  hipMemsetAsync(counts, 0, (size_t)N * 4, stream);

  detect_k<<<1, 256, 0, stream>>>((const unsigned*)vals, flag);

  int eb = (E + 255) / 256;
  hist_k<<<eb, 256, 0, stream>>>(rows, counts, E);
  scan_k<<<1, 1024, 0, stream>>>(counts, offs, cursor, N);

  scatter_k<true ><<<eb, 256, 0, stream>>>(flag, rows, cols, vals, cursor, ccol, cval, E);
  scatter_k<false><<<eb, 256, 0, stream>>>(flag, rows, cols, vals, cursor, ccol, cval, E);

  wconv_k<true ><<<256, 256, 0, stream>>>(flag, W, Wc);
  wconv_k<false><<<256, 256, 0, stream>>>(flag, W, Wc);

  int ab = (N + 3) / 4;
  agg_k<true ><<<ab, 256, 0, stream>>>(flag, emb, offs, ccol, cval, agg, N);
  agg_k<false><<<ab, 256, 0, stream>>>(flag, emb, offs, ccol, cval, agg, N);

  int gb = (N + 15) / 16;
  gemm_k<true ><<<gb, 256, 0, stream>>>(flag, agg, Wc, d_out, N);
  gemm_k<false><<<gb, 256, 0, stream>>>(flag, agg, Wc, d_out, N);
}